// Round 1
// baseline (4594.447 us; speedup 1.0000x reference)
//
#include <hip/hip_runtime.h>
#include <hip/hip_bf16.h>
#include <math.h>

#define TDS 256
#define Bq 64
#define Sq 5
#define Hq 50
#define Tq 30
#define Dq 300
#define Fq 400
#define Qq 200
#define G3 1200
#define NCAND (Bq*Sq)
#define NCLK  (Bq*Hq)
#define NTOT  (NCAND+NCLK)

__device__ __forceinline__ float sigmoidf_(float x){ return 1.f/(1.f+expf(-x)); }

// One block per title. Conv1d(SAME,W=3)+ReLU -> additive attention pool -> LayerNorm.
__global__ __launch_bounds__(256) void encode_kernel(
    const float* __restrict__ cand_emb, const float* __restrict__ clk_emb,
    const float* __restrict__ c_cw, const float* __restrict__ c_cb,
    const float* __restrict__ c_aW, const float* __restrict__ c_ab, const float* __restrict__ c_aq,
    const float* __restrict__ c_lg, const float* __restrict__ c_lb,
    const float* __restrict__ u_cw, const float* __restrict__ u_cb,
    const float* __restrict__ u_aW, const float* __restrict__ u_ab, const float* __restrict__ u_aq,
    const float* __restrict__ u_lg, const float* __restrict__ u_lb,
    float* __restrict__ cand_rep, float* __restrict__ clicked_rep)
{
  // Phase A: sbuf holds x as [d][32] (slot s = x[s-1], zero pad at s=0,31): 9600 floats.
  // Phase B (after sync): sbuf holds h as [t][400]: 12000 floats. 48KB static LDS.
  __shared__ __align__(16) float sbuf[Tq*Fq];
  __shared__ float sred[4*32];
  __shared__ float ss[32];
  __shared__ float sa[32];

  const int n = blockIdx.x;
  const bool cand = n < NCAND;
  const int tid = threadIdx.x;

  const float* x  = cand ? cand_emb + (size_t)n*Tq*Dq : clk_emb + (size_t)(n-NCAND)*Tq*Dq;
  const float* cw = cand ? c_cw : u_cw;
  const float* cb = cand ? c_cb : u_cb;
  const float* aW = cand ? c_aW : u_aW;
  const float* ab = cand ? c_ab : u_ab;
  const float* aq = cand ? c_aq : u_aq;
  const float* lg = cand ? c_lg : u_lg;
  const float* lb = cand ? c_lb : u_lb;

  // stage x -> LDS  (lanes consecutive in slot s -> conflict-free LDS writes)
  for (int i = tid; i < Dq*32; i += TDS) {
    int s = i & 31, d = i >> 5;
    float v = 0.f;
    if (s >= 1 && s <= Tq) v = x[(s-1)*Dq + d];
    sbuf[i] = v;
  }
  __syncthreads();

  const int f1 = tid;
  const int f2 = tid + 256;
  const bool f2ok = (f2 < Fq);

  float acc1[Tq], acc2[Tq];
  {
    float b1 = cb[f1];
    float b2 = f2ok ? cb[f2] : 0.f;
    #pragma unroll
    for (int t = 0; t < Tq; ++t) { acc1[t] = b1; acc2[t] = b2; }
  }

  #pragma unroll 1
  for (int d = 0; d < Dq; ++d) {
    float xv[32];
    const float4* xr = (const float4*)(sbuf + d*32);
    #pragma unroll
    for (int j = 0; j < 8; ++j) *(float4*)(xv + 4*j) = xr[j];   // LDS broadcast b128
    float w10 = cw[(0*Dq + d)*Fq + f1];
    float w11 = cw[(1*Dq + d)*Fq + f1];
    float w12 = cw[(2*Dq + d)*Fq + f1];
    #pragma unroll
    for (int t = 0; t < Tq; ++t)
      acc1[t] = fmaf(xv[t], w10, fmaf(xv[t+1], w11, fmaf(xv[t+2], w12, acc1[t])));
    if (f2ok) {
      float w20 = cw[(0*Dq + d)*Fq + f2];
      float w21 = cw[(1*Dq + d)*Fq + f2];
      float w22 = cw[(2*Dq + d)*Fq + f2];
      #pragma unroll
      for (int t = 0; t < Tq; ++t)
        acc2[t] = fmaf(xv[t], w20, fmaf(xv[t+1], w21, fmaf(xv[t+2], w22, acc2[t])));
    }
  }
  __syncthreads();            // done reading x region
  #pragma unroll
  for (int t = 0; t < Tq; ++t) {
    sbuf[t*Fq + f1] = fmaxf(acc1[t], 0.f);
    if (f2ok) sbuf[t*Fq + f2] = fmaxf(acc2[t], 0.f);
  }
  __syncthreads();

  // attention scores: s[t] = sum_q tanh(h[t]·W[:,q] + b[q]) * q[q]
  const int q = tid;
  const bool qok = q < Qq;
  float at[Tq];
  #pragma unroll
  for (int t = 0; t < Tq; ++t) at[t] = 0.f;
  if (qok) {
    #pragma unroll 1
    for (int f = 0; f < Fq; f += 4) {
      float w0 = aW[(f+0)*Qq + q];
      float w1 = aW[(f+1)*Qq + q];
      float w2 = aW[(f+2)*Qq + q];
      float w3 = aW[(f+3)*Qq + q];
      #pragma unroll
      for (int t = 0; t < Tq; ++t) {
        float4 h4 = *(const float4*)(sbuf + t*Fq + f);          // LDS broadcast
        at[t] = fmaf(h4.x,w0,fmaf(h4.y,w1,fmaf(h4.z,w2,fmaf(h4.w,w3,at[t]))));
      }
    }
  }
  const int lane = tid & 63, wv = tid >> 6;
  {
    float qv = qok ? aq[q] : 0.f;
    float bqv = qok ? ab[q] : 0.f;
    #pragma unroll
    for (int t = 0; t < Tq; ++t) {
      float vt = qok ? tanhf(at[t] + bqv) * qv : 0.f;
      #pragma unroll
      for (int off = 32; off >= 1; off >>= 1) vt += __shfl_xor(vt, off);
      if (lane == 0) sred[wv*32 + t] = vt;
    }
  }
  __syncthreads();
  if (tid < Tq) ss[tid] = sred[tid] + sred[32+tid] + sred[64+tid] + sred[96+tid];
  __syncthreads();
  if (tid < Tq) {
    float mx = -1e30f;
    #pragma unroll 1
    for (int k = 0; k < Tq; ++k) mx = fmaxf(mx, ss[k]);
    float sum = 0.f;
    #pragma unroll 1
    for (int k = 0; k < Tq; ++k) sum += expf(ss[k]-mx);
    sa[tid] = expf(ss[tid]-mx) / sum;
  }
  __syncthreads();

  // attention pooling + LayerNorm
  float rep1 = 0.f, rep2 = 0.f;
  #pragma unroll
  for (int t = 0; t < Tq; ++t) {
    float a = sa[t];
    rep1 = fmaf(a, sbuf[t*Fq+f1], rep1);
    if (f2ok) rep2 = fmaf(a, sbuf[t*Fq+f2], rep2);
  }
  float ps = rep1 + (f2ok ? rep2 : 0.f);
  float pq = rep1*rep1 + (f2ok ? rep2*rep2 : 0.f);
  #pragma unroll
  for (int off = 32; off >= 1; off >>= 1) { ps += __shfl_xor(ps, off); pq += __shfl_xor(pq, off); }
  if (lane == 0) { sred[wv] = ps; sred[4+wv] = pq; }
  __syncthreads();
  float tot = sred[0]+sred[1]+sred[2]+sred[3];
  float tsq = sred[4]+sred[5]+sred[6]+sred[7];
  float mu  = tot * (1.f/Fq);
  float var = tsq * (1.f/Fq) - mu*mu;
  float rs  = rsqrtf(var + 1e-5f);
  float* dst = cand ? cand_rep + (size_t)n*Fq : clicked_rep + (size_t)(n-NCAND)*Fq;
  dst[f1] = (rep1-mu)*rs*lg[f1] + lb[f1];
  if (f2ok) dst[f2] = (rep2-mu)*rs*lg[f2] + lb[f2];
}

// GI = clicked_rep[3200,400] @ wih^T[400,1200] + bih  (precompute all GRU input gates)
__global__ __launch_bounds__(256) void gi_kernel(
    const float* __restrict__ rep, const float* __restrict__ wih, const float* __restrict__ bih,
    float* __restrict__ gi)
{
  __shared__ __align__(16) float sA[64*80];
  const int tid = threadIdx.x;
  const int rt = blockIdx.x;                 // 0..49 (64-row tiles)
  const int g  = blockIdx.y*256 + tid;       // 0..1279
  const bool gok = g < G3;
  const float* wr = wih + (size_t)(gok ? g : 0) * Fq;
  float acc[64];
  #pragma unroll
  for (int r = 0; r < 64; ++r) acc[r] = 0.f;
  for (int kt = 0; kt < Fq; kt += 80) {
    __syncthreads();
    for (int i = tid; i < 64*80; i += 256) {
      int r = i / 80, c = i - r*80;
      sA[i] = rep[(size_t)(rt*64 + r)*Fq + kt + c];
    }
    __syncthreads();
    #pragma unroll 2
    for (int k = 0; k < 80; k += 4) {
      float w0 = wr[kt+k], w1 = wr[kt+k+1], w2 = wr[kt+k+2], w3 = wr[kt+k+3];
      #pragma unroll
      for (int r = 0; r < 64; ++r) {
        float4 a4 = *(const float4*)(sA + r*80 + k);            // LDS broadcast b128
        acc[r] = fmaf(a4.x,w0,fmaf(a4.y,w1,fmaf(a4.z,w2,fmaf(a4.w,w3,acc[r]))));
      }
    }
  }
  if (gok) {
    float bv = bih[g];
    #pragma unroll 1
    for (int r = 0; r < 64; ++r) gi[(size_t)(rt*64+r)*G3 + g] = acc[r] + bv;
  }
}

// One block per batch row. h and gates live in LDS; whh streamed from L2 each step.
__global__ __launch_bounds__(256) void gru_kernel(
    const float* __restrict__ gi, const float* __restrict__ whh, const float* __restrict__ bhh,
    const int* __restrict__ lens, float* __restrict__ user_rep)
{
  __shared__ __align__(16) float sh_[Fq];
  __shared__ float sgh[G3];
  const int b = blockIdx.x, tid = threadIdx.x;
  const int len = lens[b];
  for (int j = tid; j < Fq; j += 256) sh_[j] = 0.f;
  __syncthreads();
  const int g4 = tid + 1024;
  const bool g4ok = g4 < G3;                  // tid < 176
  const float4* wp0 = (const float4*)(whh + (size_t)(tid      )*Fq);
  const float4* wp1 = (const float4*)(whh + (size_t)(tid + 256)*Fq);
  const float4* wp2 = (const float4*)(whh + (size_t)(tid + 512)*Fq);
  const float4* wp3 = (const float4*)(whh + (size_t)(tid + 768)*Fq);
  const float4* wp4 = (const float4*)(whh + (size_t)(g4ok ? g4 : 0)*Fq);

  for (int t = 0; t < Hq; ++t) {
    if (t >= len) break;                       // frozen hereafter == reference's where()
    float a0=0.f,a1=0.f,a2=0.f,a3=0.f,a4=0.f;
    const float4* hp = (const float4*)sh_;
    #pragma unroll 2
    for (int k = 0; k < Fq/4; ++k) {
      float4 h4 = hp[k];                       // LDS broadcast
      float4 w;
      w = wp0[k]; a0 = fmaf(h4.x,w.x,fmaf(h4.y,w.y,fmaf(h4.z,w.z,fmaf(h4.w,w.w,a0))));
      w = wp1[k]; a1 = fmaf(h4.x,w.x,fmaf(h4.y,w.y,fmaf(h4.z,w.z,fmaf(h4.w,w.w,a1))));
      w = wp2[k]; a2 = fmaf(h4.x,w.x,fmaf(h4.y,w.y,fmaf(h4.z,w.z,fmaf(h4.w,w.w,a2))));
      w = wp3[k]; a3 = fmaf(h4.x,w.x,fmaf(h4.y,w.y,fmaf(h4.z,w.z,fmaf(h4.w,w.w,a3))));
      w = wp4[k]; a4 = fmaf(h4.x,w.x,fmaf(h4.y,w.y,fmaf(h4.z,w.z,fmaf(h4.w,w.w,a4))));
    }
    sgh[tid      ] = a0 + bhh[tid      ];
    sgh[tid + 256] = a1 + bhh[tid + 256];
    sgh[tid + 512] = a2 + bhh[tid + 512];
    sgh[tid + 768] = a3 + bhh[tid + 768];
    if (g4ok) sgh[g4] = a4 + bhh[g4];
    __syncthreads();
    const float* gb = gi + (size_t)(b*Hq + t)*G3;
    #pragma unroll
    for (int c = 0; c < 2; ++c) {
      int j = tid + c*256;
      if (j < Fq) {
        float r  = sigmoidf_(gb[j]        + sgh[j]);
        float z  = sigmoidf_(gb[Fq + j]   + sgh[Fq + j]);
        float nn = tanhf   (gb[2*Fq + j] + r*sgh[2*Fq + j]);
        sh_[j] = (1.f - z)*nn + z*sh_[j];
      }
    }
    __syncthreads();
  }
  for (int j = tid; j < Fq; j += 256) user_rep[b*Fq + j] = sh_[j];
}

__global__ __launch_bounds__(64) void score_kernel(
    const float* __restrict__ cand_rep, const float* __restrict__ user_rep,
    float* __restrict__ out)
{
  const int i = blockIdx.x;     // b*5+s
  const int b = i / Sq;
  const int lane = threadIdx.x;
  float acc = 0.f;
  for (int f = lane; f < Fq; f += 64) acc = fmaf(cand_rep[(size_t)i*Fq+f], user_rep[(size_t)b*Fq+f], acc);
  #pragma unroll
  for (int off = 32; off >= 1; off >>= 1) acc += __shfl_xor(acc, off);
  if (lane == 0) out[i] = acc;
}

extern "C" void kernel_launch(void* const* d_in, const int* in_sizes, int n_in,
                              void* d_out, int out_size, void* d_ws, size_t ws_size,
                              hipStream_t stream)
{
  const float* cand_emb = (const float*)d_in[0];
  const float* clk_emb  = (const float*)d_in[1];
  const int*   lens     = (const int*)  d_in[2];
  const float* c_cw = (const float*)d_in[3];
  const float* c_cb = (const float*)d_in[4];
  const float* c_aW = (const float*)d_in[5];
  const float* c_ab = (const float*)d_in[6];
  const float* c_aq = (const float*)d_in[7];
  const float* c_lg = (const float*)d_in[8];
  const float* c_lb = (const float*)d_in[9];
  const float* u_cw = (const float*)d_in[10];
  const float* u_cb = (const float*)d_in[11];
  const float* u_aW = (const float*)d_in[12];
  const float* u_ab = (const float*)d_in[13];
  const float* u_aq = (const float*)d_in[14];
  const float* u_lg = (const float*)d_in[15];
  const float* u_lb = (const float*)d_in[16];
  const float* wih  = (const float*)d_in[17];
  const float* whh  = (const float*)d_in[18];
  const float* bih  = (const float*)d_in[19];
  const float* bhh  = (const float*)d_in[20];

  float* ws = (float*)d_ws;
  float* cand_rep    = ws;                       // 320*400
  float* clicked_rep = cand_rep + NCAND*Fq;      // 3200*400
  float* gi          = clicked_rep + NCLK*Fq;    // 3200*1200
  float* user_rep    = gi + (size_t)NCLK*G3;     // 64*400

  encode_kernel<<<NTOT, 256, 0, stream>>>(
      cand_emb, clk_emb,
      c_cw, c_cb, c_aW, c_ab, c_aq, c_lg, c_lb,
      u_cw, u_cb, u_aW, u_ab, u_aq, u_lg, u_lb,
      cand_rep, clicked_rep);

  gi_kernel<<<dim3(NCLK/64, 5), 256, 0, stream>>>(clicked_rep, wih, bih, gi);

  gru_kernel<<<Bq, 256, 0, stream>>>(gi, whh, bhh, lens, user_rep);

  score_kernel<<<NCAND, 64, 0, stream>>>(cand_rep, user_rep, (float*)d_out);
}

// Round 2
// 2995.823 us; speedup vs baseline: 1.5336x; 1.5336x over previous
//
#include <hip/hip_runtime.h>
#include <hip/hip_bf16.h>
#include <math.h>

#define TDS 256
#define Bq 64
#define Sq 5
#define Hq 50
#define Tq 30
#define Dq 300
#define Fq 400
#define Qq 200
#define G3 1200
#define NCAND (Bq*Sq)
#define NCLK  (Bq*Hq)
#define NTOT  (NCAND+NCLK)

__device__ __forceinline__ float sigmoidf_(float x){ return 1.f/(1.f+expf(-x)); }

// One block per title. Conv1d(SAME,W=3)+ReLU -> additive attention pool -> LayerNorm.
__global__ __launch_bounds__(256) void encode_kernel(
    const float* __restrict__ cand_emb, const float* __restrict__ clk_emb,
    const float* __restrict__ c_cw, const float* __restrict__ c_cb,
    const float* __restrict__ c_aW, const float* __restrict__ c_ab, const float* __restrict__ c_aq,
    const float* __restrict__ c_lg, const float* __restrict__ c_lb,
    const float* __restrict__ u_cw, const float* __restrict__ u_cb,
    const float* __restrict__ u_aW, const float* __restrict__ u_ab, const float* __restrict__ u_aq,
    const float* __restrict__ u_lg, const float* __restrict__ u_lb,
    float* __restrict__ cand_rep, float* __restrict__ clicked_rep)
{
  // Phase A: sbuf holds x as [d][32] (slot s = x[s-1], zero pad at s=0,31): 9600 floats.
  // Phase B (after sync): sbuf holds h as [t][400]: 12000 floats. 48KB static LDS.
  __shared__ __align__(16) float sbuf[Tq*Fq];
  __shared__ float sred[4*32];
  __shared__ float ss[32];
  __shared__ float sa[32];

  const int n = blockIdx.x;
  const bool cand = n < NCAND;
  const int tid = threadIdx.x;

  const float* x  = cand ? cand_emb + (size_t)n*Tq*Dq : clk_emb + (size_t)(n-NCAND)*Tq*Dq;
  const float* cw = cand ? c_cw : u_cw;
  const float* cb = cand ? c_cb : u_cb;
  const float* aW = cand ? c_aW : u_aW;
  const float* ab = cand ? c_ab : u_ab;
  const float* aq = cand ? c_aq : u_aq;
  const float* lg = cand ? c_lg : u_lg;
  const float* lb = cand ? c_lb : u_lb;

  // stage x -> LDS  (lanes consecutive in slot s -> conflict-free LDS writes)
  for (int i = tid; i < Dq*32; i += TDS) {
    int s = i & 31, d = i >> 5;
    float v = 0.f;
    if (s >= 1 && s <= Tq) v = x[(s-1)*Dq + d];
    sbuf[i] = v;
  }
  __syncthreads();

  const int f1 = tid;
  const int f2 = tid + 256;
  const bool f2ok = (f2 < Fq);

  float acc1[Tq], acc2[Tq];
  {
    float b1 = cb[f1];
    float b2 = f2ok ? cb[f2] : 0.f;
    #pragma unroll
    for (int t = 0; t < Tq; ++t) { acc1[t] = b1; acc2[t] = b2; }
  }

  #pragma unroll 1
  for (int d = 0; d < Dq; ++d) {
    float xv[32];
    const float4* xr = (const float4*)(sbuf + d*32);
    #pragma unroll
    for (int j = 0; j < 8; ++j) *(float4*)(xv + 4*j) = xr[j];   // LDS broadcast b128
    float w10 = cw[(0*Dq + d)*Fq + f1];
    float w11 = cw[(1*Dq + d)*Fq + f1];
    float w12 = cw[(2*Dq + d)*Fq + f1];
    #pragma unroll
    for (int t = 0; t < Tq; ++t)
      acc1[t] = fmaf(xv[t], w10, fmaf(xv[t+1], w11, fmaf(xv[t+2], w12, acc1[t])));
    if (f2ok) {
      float w20 = cw[(0*Dq + d)*Fq + f2];
      float w21 = cw[(1*Dq + d)*Fq + f2];
      float w22 = cw[(2*Dq + d)*Fq + f2];
      #pragma unroll
      for (int t = 0; t < Tq; ++t)
        acc2[t] = fmaf(xv[t], w20, fmaf(xv[t+1], w21, fmaf(xv[t+2], w22, acc2[t])));
    }
  }
  __syncthreads();            // done reading x region
  #pragma unroll
  for (int t = 0; t < Tq; ++t) {
    sbuf[t*Fq + f1] = fmaxf(acc1[t], 0.f);
    if (f2ok) sbuf[t*Fq + f2] = fmaxf(acc2[t], 0.f);
  }
  __syncthreads();

  // attention scores: s[t] = sum_q tanh(h[t]·W[:,q] + b[q]) * q[q]
  const int q = tid;
  const bool qok = q < Qq;
  float at[Tq];
  #pragma unroll
  for (int t = 0; t < Tq; ++t) at[t] = 0.f;
  if (qok) {
    #pragma unroll 1
    for (int f = 0; f < Fq; f += 4) {
      float w0 = aW[(f+0)*Qq + q];
      float w1 = aW[(f+1)*Qq + q];
      float w2 = aW[(f+2)*Qq + q];
      float w3 = aW[(f+3)*Qq + q];
      #pragma unroll
      for (int t = 0; t < Tq; ++t) {
        float4 h4 = *(const float4*)(sbuf + t*Fq + f);          // LDS broadcast
        at[t] = fmaf(h4.x,w0,fmaf(h4.y,w1,fmaf(h4.z,w2,fmaf(h4.w,w3,at[t]))));
      }
    }
  }
  const int lane = tid & 63, wv = tid >> 6;
  {
    float qv = qok ? aq[q] : 0.f;
    float bqv = qok ? ab[q] : 0.f;
    #pragma unroll
    for (int t = 0; t < Tq; ++t) {
      float vt = qok ? tanhf(at[t] + bqv) * qv : 0.f;
      #pragma unroll
      for (int off = 32; off >= 1; off >>= 1) vt += __shfl_xor(vt, off);
      if (lane == 0) sred[wv*32 + t] = vt;
    }
  }
  __syncthreads();
  if (tid < Tq) ss[tid] = sred[tid] + sred[32+tid] + sred[64+tid] + sred[96+tid];
  __syncthreads();
  if (tid < Tq) {
    float mx = -1e30f;
    #pragma unroll 1
    for (int k = 0; k < Tq; ++k) mx = fmaxf(mx, ss[k]);
    float sum = 0.f;
    #pragma unroll 1
    for (int k = 0; k < Tq; ++k) sum += expf(ss[k]-mx);
    sa[tid] = expf(ss[tid]-mx) / sum;
  }
  __syncthreads();

  // attention pooling + LayerNorm
  float rep1 = 0.f, rep2 = 0.f;
  #pragma unroll
  for (int t = 0; t < Tq; ++t) {
    float a = sa[t];
    rep1 = fmaf(a, sbuf[t*Fq+f1], rep1);
    if (f2ok) rep2 = fmaf(a, sbuf[t*Fq+f2], rep2);
  }
  float ps = rep1 + (f2ok ? rep2 : 0.f);
  float pq = rep1*rep1 + (f2ok ? rep2*rep2 : 0.f);
  #pragma unroll
  for (int off = 32; off >= 1; off >>= 1) { ps += __shfl_xor(ps, off); pq += __shfl_xor(pq, off); }
  if (lane == 0) { sred[wv] = ps; sred[4+wv] = pq; }
  __syncthreads();
  float tot = sred[0]+sred[1]+sred[2]+sred[3];
  float tsq = sred[4]+sred[5]+sred[6]+sred[7];
  float mu  = tot * (1.f/Fq);
  float var = tsq * (1.f/Fq) - mu*mu;
  float rs  = rsqrtf(var + 1e-5f);
  float* dst = cand ? cand_rep + (size_t)n*Fq : clicked_rep + (size_t)(n-NCAND)*Fq;
  dst[f1] = (rep1-mu)*rs*lg[f1] + lb[f1];
  if (f2ok) dst[f2] = (rep2-mu)*rs*lg[f2] + lb[f2];
}

// GI = clicked_rep[3200,400] @ wih^T[400,1200] + bih  (precompute all GRU input gates)
__global__ __launch_bounds__(256) void gi_kernel(
    const float* __restrict__ rep, const float* __restrict__ wih, const float* __restrict__ bih,
    float* __restrict__ gi)
{
  __shared__ __align__(16) float sA[64*80];
  const int tid = threadIdx.x;
  const int rt = blockIdx.x;                 // 0..49 (64-row tiles)
  const int g  = blockIdx.y*256 + tid;       // 0..1279
  const bool gok = g < G3;
  const float* wr = wih + (size_t)(gok ? g : 0) * Fq;
  float acc[64];
  #pragma unroll
  for (int r = 0; r < 64; ++r) acc[r] = 0.f;
  for (int kt = 0; kt < Fq; kt += 80) {
    __syncthreads();
    for (int i = tid; i < 64*80; i += 256) {
      int r = i / 80, c = i - r*80;
      sA[i] = rep[(size_t)(rt*64 + r)*Fq + kt + c];
    }
    __syncthreads();
    #pragma unroll 2
    for (int k = 0; k < 80; k += 4) {
      float w0 = wr[kt+k], w1 = wr[kt+k+1], w2 = wr[kt+k+2], w3 = wr[kt+k+3];
      #pragma unroll
      for (int r = 0; r < 64; ++r) {
        float4 a4 = *(const float4*)(sA + r*80 + k);            // LDS broadcast b128
        acc[r] = fmaf(a4.x,w0,fmaf(a4.y,w1,fmaf(a4.z,w2,fmaf(a4.w,w3,acc[r]))));
      }
    }
  }
  if (gok) {
    float bv = bih[g];
    #pragma unroll 1
    for (int r = 0; r < 64; ++r) gi[(size_t)(rt*64+r)*G3 + g] = acc[r] + bv;
  }
}

// One-time transpose of whh [1200,400] into [k/4][g][4] so GRU weight loads are
// coalesced: wave of consecutive g reading float4 at (k4*1200+g) = 1KB contiguous.
__global__ __launch_bounds__(1024) void whh_transpose_kernel(
    const float* __restrict__ whh, float* __restrict__ whhT4)
{
  int i = blockIdx.x*1024 + threadIdx.x;
  if (i < G3*Fq) {
    int k4  = i / (G3*4);
    int rem = i - k4*(G3*4);
    int g   = rem >> 2;
    int kk  = rem & 3;
    whhT4[i] = whh[(size_t)g*Fq + k4*4 + kk];
  }
}

// One block per batch row, 1024 threads (16 waves). h + gates in LDS; whhT4
// streamed (L2-resident, fully coalesced float4). Thread owns gate tid
// (+ tid+1024 for tid<176).
__global__ __launch_bounds__(1024) void gru_kernel(
    const float* __restrict__ gi, const float* __restrict__ whhT4, const float* __restrict__ bhh,
    const int* __restrict__ lens, float* __restrict__ user_rep)
{
  __shared__ __align__(16) float sh_[Fq];
  __shared__ float sgh[G3];
  const int b = blockIdx.x, tid = threadIdx.x;
  const int len = lens[b];
  for (int j = tid; j < Fq; j += 1024) sh_[j] = 0.f;
  __syncthreads();
  const int g2 = tid + 1024;
  const bool g2ok = (g2 < G3);                 // tid < 176
  const float4* w0 = (const float4*)whhT4 + tid;
  const float4* w1 = (const float4*)whhT4 + (g2ok ? g2 : tid);
  const float bb0 = bhh[tid];
  const float bb1 = g2ok ? bhh[g2] : 0.f;
  const float* gb = gi + (size_t)b*Hq*G3;

  for (int t = 0; t < len; ++t) {
    float a0 = 0.f, a1 = 0.f;
    const float4* hp = (const float4*)sh_;
    #pragma unroll 4
    for (int k = 0; k < Fq/4; ++k) {
      float4 h4 = hp[k];                       // LDS broadcast
      float4 w = w0[(size_t)k*G3];             // coalesced 1KB/wave
      a0 = fmaf(h4.x,w.x,fmaf(h4.y,w.y,fmaf(h4.z,w.z,fmaf(h4.w,w.w,a0))));
      if (g2ok) {
        float4 v = w1[(size_t)k*G3];
        a1 = fmaf(h4.x,v.x,fmaf(h4.y,v.y,fmaf(h4.z,v.z,fmaf(h4.w,v.w,a1))));
      }
    }
    sgh[tid] = a0 + bb0;
    if (g2ok) sgh[g2] = a1 + bb1;
    __syncthreads();
    if (tid < Fq) {
      int j = tid;
      float r  = sigmoidf_(gb[j]         + sgh[j]);
      float z  = sigmoidf_(gb[Fq + j]    + sgh[Fq + j]);
      float nn = tanhf   (gb[2*Fq + j]  + r*sgh[2*Fq + j]);
      sh_[j] = (1.f - z)*nn + z*sh_[j];
    }
    __syncthreads();
    gb += G3;
  }
  for (int j = tid; j < Fq; j += 1024) user_rep[(size_t)b*Fq + j] = sh_[j];
}

__global__ __launch_bounds__(64) void score_kernel(
    const float* __restrict__ cand_rep, const float* __restrict__ user_rep,
    float* __restrict__ out)
{
  const int i = blockIdx.x;     // b*5+s
  const int b = i / Sq;
  const int lane = threadIdx.x;
  float acc = 0.f;
  for (int f = lane; f < Fq; f += 64) acc = fmaf(cand_rep[(size_t)i*Fq+f], user_rep[(size_t)b*Fq+f], acc);
  #pragma unroll
  for (int off = 32; off >= 1; off >>= 1) acc += __shfl_xor(acc, off);
  if (lane == 0) out[i] = acc;
}

extern "C" void kernel_launch(void* const* d_in, const int* in_sizes, int n_in,
                              void* d_out, int out_size, void* d_ws, size_t ws_size,
                              hipStream_t stream)
{
  const float* cand_emb = (const float*)d_in[0];
  const float* clk_emb  = (const float*)d_in[1];
  const int*   lens     = (const int*)  d_in[2];
  const float* c_cw = (const float*)d_in[3];
  const float* c_cb = (const float*)d_in[4];
  const float* c_aW = (const float*)d_in[5];
  const float* c_ab = (const float*)d_in[6];
  const float* c_aq = (const float*)d_in[7];
  const float* c_lg = (const float*)d_in[8];
  const float* c_lb = (const float*)d_in[9];
  const float* u_cw = (const float*)d_in[10];
  const float* u_cb = (const float*)d_in[11];
  const float* u_aW = (const float*)d_in[12];
  const float* u_ab = (const float*)d_in[13];
  const float* u_aq = (const float*)d_in[14];
  const float* u_lg = (const float*)d_in[15];
  const float* u_lb = (const float*)d_in[16];
  const float* wih  = (const float*)d_in[17];
  const float* whh  = (const float*)d_in[18];
  const float* bih  = (const float*)d_in[19];
  const float* bhh  = (const float*)d_in[20];

  float* ws = (float*)d_ws;
  float* cand_rep    = ws;                       // 320*400
  float* clicked_rep = cand_rep + NCAND*Fq;      // 3200*400
  float* gi          = clicked_rep + NCLK*Fq;    // 3200*1200
  float* user_rep    = gi + (size_t)NCLK*G3;     // 64*400
  float* whhT4       = user_rep + Bq*Fq;         // 1200*400

  encode_kernel<<<NTOT, 256, 0, stream>>>(
      cand_emb, clk_emb,
      c_cw, c_cb, c_aW, c_ab, c_aq, c_lg, c_lb,
      u_cw, u_cb, u_aW, u_ab, u_aq, u_lg, u_lb,
      cand_rep, clicked_rep);

  whh_transpose_kernel<<<(G3*Fq + 1023)/1024, 1024, 0, stream>>>(whh, whhT4);

  gi_kernel<<<dim3(NCLK/64, 5), 256, 0, stream>>>(clicked_rep, wih, bih, gi);

  gru_kernel<<<Bq, 1024, 0, stream>>>(gi, whhT4, bhh, lens, user_rep);

  score_kernel<<<NCAND, 64, 0, stream>>>(cand_rep, user_rep, (float*)d_out);
}

// Round 3
// 1400.046 us; speedup vs baseline: 3.2816x; 2.1398x over previous
//
#include <hip/hip_runtime.h>
#include <hip/hip_bf16.h>
#include <math.h>

#define Bq 64
#define Sq 5
#define Hq 50
#define Tq 30
#define Dq 300
#define Fq 400
#define Qq 200
#define G3 1200
#define NCAND (Bq*Sq)
#define NCLK  (Bq*Hq)

typedef __attribute__((ext_vector_type(8))) short bf16x8;
typedef __attribute__((ext_vector_type(4))) float f32x4;

__device__ __forceinline__ float sigmoidf_(float x){ return 1.f/(1.f+expf(-x)); }
__device__ __forceinline__ unsigned short f2bf(float x){
  __hip_bfloat16 b = __float2bfloat16(x);
  return *reinterpret_cast<unsigned short*>(&b);
}
__device__ __forceinline__ float bf2f(unsigned short u){
  __hip_bfloat16 b; *reinterpret_cast<unsigned short*>(&b) = u;
  return __bfloat162float(b);
}

// ---------------- weight prep (one-time per call, tiny) ----------------
// conv weights -> bf16 chunks [2 enc][30 chunks][4 sub][512 col][8 j], zero-padded.
// chunk = w*10+s covers d = s*32 + sub*8 + j (d<300 valid), col = filter (<400 valid).
__global__ __launch_bounds__(256) void conv_prep_kernel(
    const float* __restrict__ c_cw, const float* __restrict__ u_cw,
    __hip_bfloat16* __restrict__ out)
{
  const int PER = 30*16384;
  int idx = blockIdx.x*256 + threadIdx.x;
  if (idx >= 2*PER) return;
  int enc = idx / PER, rem = idx - enc*PER;
  int chunk = rem >> 14;
  int e = rem & 16383;
  int sub = e >> 12;
  int col = (e >> 3) & 511;
  int j = e & 7;
  int w = chunk / 10, s = chunk - w*10;
  int d = s*32 + sub*8 + j;
  const float* cw = enc ? u_cw : c_cw;
  float v = (d < Dq && col < Fq) ? cw[(w*Dq + d)*Fq + col] : 0.f;
  out[idx] = __float2bfloat16(v);
}

// att_W -> bf16 chunks [2 enc][13 chunks][4 sub][256 col][8 j], k = f (<400), col = q (<200)
__global__ __launch_bounds__(256) void att_prep_kernel(
    const float* __restrict__ c_aW, const float* __restrict__ u_aW,
    __hip_bfloat16* __restrict__ out)
{
  const int PER = 13*8192;
  int idx = blockIdx.x*256 + threadIdx.x;
  if (idx >= 2*PER) return;
  int enc = idx / PER, rem = idx - enc*PER;
  int chunk = rem >> 13;
  int e = rem & 8191;
  int sub = e >> 11;
  int col = (e >> 3) & 255;
  int j = e & 7;
  int k = chunk*32 + sub*8 + j;
  const float* aW = enc ? u_aW : c_aW;
  float v = (k < Fq && col < Qq) ? aW[k*Qq + col] : 0.f;
  out[idx] = __float2bfloat16(v);
}

// ---------------- fused encoder: conv(MFMA) + attention(MFMA) + softmax + pool + LN ---------
// 880 blocks x 512 threads; 4 titles per block.
// LDS map (bytes):
//  [0, 87680)         x_lds [40 chunk][137 row][8 bf16]  (conv A; rows = title*32 + (t+1), 128..136 zero)
//  [87680, 120448)    conv B buf0  [4 sub][512 col][8]
//  [120448, 153216)   conv B buf1
//  [0, 106496)        H [52 fchunk][128 row][8 bf16]     (after conv; attention A + pooling)
//  [106496, 122880)   att B buf0   [4 sub][256 col][8]
//  [122880, 139264)   att B buf1
//  [153216, 154304)   scratch: sscore[128] sa[128] red[16] (f32)
#define XROWS 137
#define XBYTES (40*XROWS*16)
#define BBUF0 XBYTES
#define BCHUNK 32768
#define BBUF1 (BBUF0 + BCHUNK)
#define ABUF0 (52*128*16)
#define ACHUNK 16384
#define ABUF1 (ABUF0 + ACHUNK)
#define SCRATCH (BBUF1 + BCHUNK)
#define SMEM_BYTES (SCRATCH + 1088)

__global__ __launch_bounds__(512, 2) void encode_mfma_kernel(
    const float* __restrict__ cand_emb, const float* __restrict__ clk_emb,
    const __hip_bfloat16* __restrict__ convprep,  // [2][30*16384]
    const __hip_bfloat16* __restrict__ attprep,   // [2][13*8192]
    const float* __restrict__ c_cb, const float* __restrict__ c_ab, const float* __restrict__ c_aq,
    const float* __restrict__ c_lg, const float* __restrict__ c_lb,
    const float* __restrict__ u_cb, const float* __restrict__ u_ab, const float* __restrict__ u_aq,
    const float* __restrict__ u_lg, const float* __restrict__ u_lb,
    float* __restrict__ cand_rep, float* __restrict__ clicked_rep)
{
  __shared__ __align__(16) unsigned char smem[SMEM_BYTES];
  float* sscore = (float*)(smem + SCRATCH);
  float* sa_    = sscore + 128;
  float* red_   = sa_ + 128;

  const int b = blockIdx.x, tid = threadIdx.x;
  const bool cand = b < (NCAND/4);
  const int n0 = cand ? b*4 : (b - NCAND/4)*4;
  const float* x = (cand ? cand_emb : clk_emb) + (size_t)n0*Tq*Dq;
  const __hip_bfloat16* Wp = convprep + (cand ? 0 : 30*16384);
  const __hip_bfloat16* Ap = attprep  + (cand ? 0 : 13*8192);
  const float* cb = cand ? c_cb : u_cb;
  const float* ab = cand ? c_ab : u_ab;
  const float* aq = cand ? c_aq : u_aq;
  const float* lg = cand ? c_lg : u_lg;
  const float* lb = cand ? c_lb : u_lb;

  const int lane = tid & 63, wid = tid >> 6;
  const int mh = wid >> 2, nq = wid & 3;
  const int l15 = lane & 15, l4 = lane >> 4;

  if (tid < 128) sscore[tid] = 0.f;

  // ---- stage x -> bf16 LDS [chunk][row][8] ----
  for (int i = tid; i < 40*XROWS; i += 512) {
    int c = i % 40, r = i / 40;
    float4 va = {0.f,0.f,0.f,0.f}, vb = {0.f,0.f,0.f,0.f};
    if (r < 128) {
      int lr = r & 31, tt = r >> 5;
      if (lr >= 1 && lr <= 30) {
        int t = lr - 1, d0 = c*8;
        if (d0 < Dq) {
          const float* src = x + (size_t)tt*Tq*Dq + t*Dq + d0;
          va = *(const float4*)src;
          if (d0 + 4 < Dq) vb = *(const float4*)(src + 4);
        }
      }
    }
    union { bf16x8 v; unsigned short u[8]; } pk;
    pk.u[0]=f2bf(va.x); pk.u[1]=f2bf(va.y); pk.u[2]=f2bf(va.z); pk.u[3]=f2bf(va.w);
    pk.u[4]=f2bf(vb.x); pk.u[5]=f2bf(vb.y); pk.u[6]=f2bf(vb.z); pk.u[7]=f2bf(vb.w);
    *(bf16x8*)(smem + (size_t)(c*XROWS + r)*16) = pk.v;
  }

  // ---- conv accumulators (+bias) ----
  f32x4 acc[4][7];
  float cbv[7];
  #pragma unroll
  for (int nf = 0; nf < 7; ++nf) {
    int colg = (nq*7 + nf)*16 + l15;
    cbv[nf] = (colg < Fq) ? cb[colg] : 0.f;
  }
  #pragma unroll
  for (int mf = 0; mf < 4; ++mf)
    #pragma unroll
    for (int nf = 0; nf < 7; ++nf)
      acc[mf][nf] = (f32x4){cbv[nf], cbv[nf], cbv[nf], cbv[nf]};

  // stage conv B chunk 0
  {
    const __hip_bfloat16* src = Wp;
    #pragma unroll
    for (int k = 0; k < 4; ++k) {
      uint4 v = *(const uint4*)(src + k*4096 + tid*8);
      *(uint4*)(smem + BBUF0 + k*8192 + tid*16) = v;
    }
  }
  __syncthreads();

  // ---- conv main loop: 30 K-steps (w=0..2, s=0..9) ----
  for (int step = 0; step < 30; ++step) {
    const int w = step / 10, s = step - w*10;
    const int cbuf = step & 1;
    uint4 nx0, nx1, nx2, nx3;
    const bool have = (step < 29);
    if (have) {
      const __hip_bfloat16* src = Wp + (size_t)(step+1)*16384;
      nx0 = *(const uint4*)(src + 0*4096 + tid*8);
      nx1 = *(const uint4*)(src + 1*4096 + tid*8);
      nx2 = *(const uint4*)(src + 2*4096 + tid*8);
      nx3 = *(const uint4*)(src + 3*4096 + tid*8);
    }
    bf16x8 a[4];
    #pragma unroll
    for (int mf = 0; mf < 4; ++mf) {
      int arow = mh*64 + mf*16 + l15 + w;
      int c = s*4 + l4;
      a[mf] = *(const bf16x8*)(smem + (size_t)(c*XROWS + arow)*16);
    }
    bf16x8 bb[7];
    const unsigned char* bbase = smem + (cbuf ? BBUF1 : BBUF0);
    #pragma unroll
    for (int nf = 0; nf < 7; ++nf) {
      int col = (nq*7 + nf)*16 + l15;
      bb[nf] = *(const bf16x8*)(bbase + (size_t)(l4*512 + col)*16);
    }
    #pragma unroll
    for (int mf = 0; mf < 4; ++mf)
      #pragma unroll
      for (int nf = 0; nf < 7; ++nf)
        acc[mf][nf] = __builtin_amdgcn_mfma_f32_16x16x32_bf16(a[mf], bb[nf], acc[mf][nf], 0, 0, 0);
    if (have) {
      unsigned char* obase = smem + (cbuf ? BBUF0 : BBUF1);
      *(uint4*)(obase + 0*8192 + tid*16) = nx0;
      *(uint4*)(obase + 1*8192 + tid*16) = nx1;
      *(uint4*)(obase + 2*8192 + tid*16) = nx2;
      *(uint4*)(obase + 3*8192 + tid*16) = nx3;
    }
    __syncthreads();
  }

  // ---- stage att chunk 0, store H = relu(acc) as bf16 [fchunk][row][8] ----
  {
    #pragma unroll
    for (int k = 0; k < 2; ++k) {
      uint4 v = *(const uint4*)(Ap + k*4096 + tid*8);
      *(uint4*)(smem + ABUF0 + k*8192 + tid*16) = v;
    }
  }
  #pragma unroll
  for (int mf = 0; mf < 4; ++mf) {
    #pragma unroll
    for (int nf = 0; nf < 7; ++nf) {
      int colg = (nq*7 + nf)*16 + l15;
      if (colg < 416) {
        #pragma unroll
        for (int i = 0; i < 4; ++i) {
          int row = mh*64 + mf*16 + l4*4 + i;
          float v = fmaxf(acc[mf][nf][i], 0.f);
          *(unsigned short*)(smem + (size_t)((colg >> 3)*128 + row)*16 + (colg & 7)*2) = f2bf(v);
        }
      }
    }
  }
  __syncthreads();

  // ---- attention GEMM: S[128 t][208 q] = H[128][416] @ attW[416][208] ----
  f32x4 acc2[4][4];
  #pragma unroll
  for (int mf = 0; mf < 4; ++mf)
    #pragma unroll
    for (int nn = 0; nn < 4; ++nn)
      acc2[mf][nn] = (f32x4){0.f,0.f,0.f,0.f};
  const int nf0  = (nq == 0) ? 0 : (1 + 3*nq);   // 0,4,7,10
  const int ncnt = (nq == 0) ? 4 : 3;

  for (int s2 = 0; s2 < 13; ++s2) {
    const int cbuf = s2 & 1;
    uint4 nx0, nx1;
    const bool have = (s2 < 12);
    if (have) {
      const __hip_bfloat16* src = Ap + (size_t)(s2+1)*8192;
      nx0 = *(const uint4*)(src + 0*4096 + tid*8);
      nx1 = *(const uint4*)(src + 1*4096 + tid*8);
    }
    bf16x8 a2[4];
    #pragma unroll
    for (int mf = 0; mf < 4; ++mf) {
      int row = mh*64 + mf*16 + l15;
      int fchunk = s2*4 + l4;
      a2[mf] = *(const bf16x8*)(smem + (size_t)(fchunk*128 + row)*16);
    }
    bf16x8 b2[4];
    const unsigned char* bbase = smem + (cbuf ? ABUF1 : ABUF0);
    #pragma unroll
    for (int nn = 0; nn < 4; ++nn) {
      if (nn < ncnt) {
        int col = (nf0 + nn)*16 + l15;
        b2[nn] = *(const bf16x8*)(bbase + (size_t)(l4*256 + col)*16);
      }
    }
    #pragma unroll
    for (int mf = 0; mf < 4; ++mf)
      #pragma unroll
      for (int nn = 0; nn < 4; ++nn)
        if (nn < ncnt)
          acc2[mf][nn] = __builtin_amdgcn_mfma_f32_16x16x32_bf16(a2[mf], b2[nn], acc2[mf][nn], 0, 0, 0);
    if (have) {
      unsigned char* obase = smem + (cbuf ? ABUF0 : ABUF1);
      *(uint4*)(obase + 0*8192 + tid*16) = nx0;
      *(uint4*)(obase + 1*8192 + tid*16) = nx1;
    }
    __syncthreads();
  }

  // ---- tanh + aq reduce -> per-row score ----
  {
    float abv[4], aqv[4];
    #pragma unroll
    for (int nn = 0; nn < 4; ++nn) {
      int col = (nf0 + nn)*16 + l15;
      bool ok = (nn < ncnt) && (col < Qq);
      abv[nn] = ok ? ab[col] : 0.f;
      aqv[nn] = ok ? aq[col] : 0.f;
    }
    #pragma unroll
    for (int mf = 0; mf < 4; ++mf) {
      #pragma unroll
      for (int i = 0; i < 4; ++i) {
        float p = 0.f;
        #pragma unroll
        for (int nn = 0; nn < 4; ++nn)
          if (nn < ncnt)
            p += tanhf(acc2[mf][nn][i] + abv[nn]) * aqv[nn];
        p += __shfl_xor(p, 1); p += __shfl_xor(p, 2);
        p += __shfl_xor(p, 4); p += __shfl_xor(p, 8);
        if (l15 == 0) atomicAdd(&sscore[mh*64 + mf*16 + l4*4 + i], p);
      }
    }
  }
  __syncthreads();

  // ---- softmax over t per title ----
  if (tid < 4) {
    float mx = -1e30f;
    for (int t = 0; t < Tq; ++t) mx = fmaxf(mx, sscore[tid*32 + t]);
    float sum = 0.f;
    for (int t = 0; t < Tq; ++t) { float e = expf(sscore[tid*32 + t] - mx); sa_[tid*32 + t] = e; sum += e; }
    float inv = 1.f / sum;
    for (int t = 0; t < Tq; ++t) sa_[tid*32 + t] *= inv;
    sa_[tid*32 + 30] = 0.f; sa_[tid*32 + 31] = 0.f;
  }
  __syncthreads();

  // ---- pooling + LayerNorm ----
  {
    const int tt = tid >> 7, fb = tid & 127;
    float rv[4];
    float ls = 0.f, lsq = 0.f;
    #pragma unroll
    for (int q = 0; q < 4; ++q) {
      int f = fb + q*128;
      rv[q] = 0.f;
      if (f < Fq) {
        float r = 0.f;
        const unsigned char* hb = smem + (size_t)(f >> 3)*128*16 + (f & 7)*2;
        for (int t = 0; t < Tq; ++t)
          r += sa_[tt*32 + t] * bf2f(*(const unsigned short*)(hb + (size_t)(tt*32 + t)*16));
        rv[q] = r; ls += r; lsq += r*r;
      }
    }
    #pragma unroll
    for (int off = 32; off >= 1; off >>= 1) { ls += __shfl_xor(ls, off); lsq += __shfl_xor(lsq, off); }
    if (lane == 0) { red_[wid] = ls; red_[8 + wid] = lsq; }
    __syncthreads();
    float tot  = red_[2*tt] + red_[2*tt + 1];
    float totq = red_[8 + 2*tt] + red_[8 + 2*tt + 1];
    float mu = tot * (1.f/Fq);
    float var = totq * (1.f/Fq) - mu*mu;
    float rs = rsqrtf(var + 1e-5f);
    float* dst = (cand ? cand_rep : clicked_rep) + (size_t)(n0 + tt)*Fq;
    #pragma unroll
    for (int q = 0; q < 4; ++q) {
      int f = fb + q*128;
      if (f < Fq) dst[f] = (rv[q] - mu)*rs*lg[f] + lb[f];
    }
  }
}

// ---------------- GI = clicked_rep @ wih^T + bih ----------------
__global__ __launch_bounds__(256) void gi_kernel(
    const float* __restrict__ rep, const float* __restrict__ wih, const float* __restrict__ bih,
    float* __restrict__ gi)
{
  __shared__ __align__(16) float sA[64*80];
  const int tid = threadIdx.x;
  const int rt = blockIdx.x;
  const int g  = blockIdx.y*256 + tid;
  const bool gok = g < G3;
  const float* wr = wih + (size_t)(gok ? g : 0) * Fq;
  float acc[64];
  #pragma unroll
  for (int r = 0; r < 64; ++r) acc[r] = 0.f;
  for (int kt = 0; kt < Fq; kt += 80) {
    __syncthreads();
    for (int i = tid; i < 64*80; i += 256) {
      int r = i / 80, c = i - r*80;
      sA[i] = rep[(size_t)(rt*64 + r)*Fq + kt + c];
    }
    __syncthreads();
    #pragma unroll 2
    for (int k = 0; k < 80; k += 4) {
      float w0 = wr[kt+k], w1 = wr[kt+k+1], w2 = wr[kt+k+2], w3 = wr[kt+k+3];
      #pragma unroll
      for (int r = 0; r < 64; ++r) {
        float4 a4 = *(const float4*)(sA + r*80 + k);
        acc[r] = fmaf(a4.x,w0,fmaf(a4.y,w1,fmaf(a4.z,w2,fmaf(a4.w,w3,acc[r]))));
      }
    }
  }
  if (gok) {
    float bv = bih[g];
    #pragma unroll 1
    for (int r = 0; r < 64; ++r) gi[(size_t)(rt*64+r)*G3 + g] = acc[r] + bv;
  }
}

__global__ __launch_bounds__(1024) void whh_transpose_kernel(
    const float* __restrict__ whh, float* __restrict__ whhT4)
{
  int i = blockIdx.x*1024 + threadIdx.x;
  if (i < G3*Fq) {
    int k4  = i / (G3*4);
    int rem = i - k4*(G3*4);
    int g   = rem >> 2;
    int kk  = rem & 3;
    whhT4[i] = whh[(size_t)g*Fq + k4*4 + kk];
  }
}

__global__ __launch_bounds__(1024) void gru_kernel(
    const float* __restrict__ gi, const float* __restrict__ whhT4, const float* __restrict__ bhh,
    const int* __restrict__ lens, float* __restrict__ user_rep)
{
  __shared__ __align__(16) float sh_[Fq];
  __shared__ float sgh[G3];
  const int b = blockIdx.x, tid = threadIdx.x;
  const int len = lens[b];
  for (int j = tid; j < Fq; j += 1024) sh_[j] = 0.f;
  __syncthreads();
  const int g2 = tid + 1024;
  const bool g2ok = (g2 < G3);
  const float4* w0 = (const float4*)whhT4 + tid;
  const float4* w1 = (const float4*)whhT4 + (g2ok ? g2 : tid);
  const float bb0 = bhh[tid];
  const float bb1 = g2ok ? bhh[g2] : 0.f;
  const float* gb = gi + (size_t)b*Hq*G3;

  for (int t = 0; t < len; ++t) {
    float a0 = 0.f, a1 = 0.f;
    const float4* hp = (const float4*)sh_;
    #pragma unroll 4
    for (int k = 0; k < Fq/4; ++k) {
      float4 h4 = hp[k];
      float4 w = w0[(size_t)k*G3];
      a0 = fmaf(h4.x,w.x,fmaf(h4.y,w.y,fmaf(h4.z,w.z,fmaf(h4.w,w.w,a0))));
      if (g2ok) {
        float4 v = w1[(size_t)k*G3];
        a1 = fmaf(h4.x,v.x,fmaf(h4.y,v.y,fmaf(h4.z,v.z,fmaf(h4.w,v.w,a1))));
      }
    }
    sgh[tid] = a0 + bb0;
    if (g2ok) sgh[g2] = a1 + bb1;
    __syncthreads();
    if (tid < Fq) {
      int j = tid;
      float r  = sigmoidf_(gb[j]        + sgh[j]);
      float z  = sigmoidf_(gb[Fq + j]   + sgh[Fq + j]);
      float nn = tanhf   (gb[2*Fq + j] + r*sgh[2*Fq + j]);
      sh_[j] = (1.f - z)*nn + z*sh_[j];
    }
    __syncthreads();
    gb += G3;
  }
  for (int j = tid; j < Fq; j += 1024) user_rep[(size_t)b*Fq + j] = sh_[j];
}

__global__ __launch_bounds__(64) void score_kernel(
    const float* __restrict__ cand_rep, const float* __restrict__ user_rep,
    float* __restrict__ out)
{
  const int i = blockIdx.x;
  const int b = i / Sq;
  const int lane = threadIdx.x;
  float acc = 0.f;
  for (int f = lane; f < Fq; f += 64) acc = fmaf(cand_rep[(size_t)i*Fq+f], user_rep[(size_t)b*Fq+f], acc);
  #pragma unroll
  for (int off = 32; off >= 1; off >>= 1) acc += __shfl_xor(acc, off);
  if (lane == 0) out[i] = acc;
}

extern "C" void kernel_launch(void* const* d_in, const int* in_sizes, int n_in,
                              void* d_out, int out_size, void* d_ws, size_t ws_size,
                              hipStream_t stream)
{
  const float* cand_emb = (const float*)d_in[0];
  const float* clk_emb  = (const float*)d_in[1];
  const int*   lens     = (const int*)  d_in[2];
  const float* c_cw = (const float*)d_in[3];
  const float* c_cb = (const float*)d_in[4];
  const float* c_aW = (const float*)d_in[5];
  const float* c_ab = (const float*)d_in[6];
  const float* c_aq = (const float*)d_in[7];
  const float* c_lg = (const float*)d_in[8];
  const float* c_lb = (const float*)d_in[9];
  const float* u_cw = (const float*)d_in[10];
  const float* u_cb = (const float*)d_in[11];
  const float* u_aW = (const float*)d_in[12];
  const float* u_ab = (const float*)d_in[13];
  const float* u_aq = (const float*)d_in[14];
  const float* u_lg = (const float*)d_in[15];
  const float* u_lb = (const float*)d_in[16];
  const float* wih  = (const float*)d_in[17];
  const float* whh  = (const float*)d_in[18];
  const float* bih  = (const float*)d_in[19];
  const float* bhh  = (const float*)d_in[20];

  float* ws = (float*)d_ws;
  float* cand_rep    = ws;                       // 320*400
  float* clicked_rep = cand_rep + NCAND*Fq;      // 3200*400
  float* gi          = clicked_rep + NCLK*Fq;    // 3200*1200
  float* user_rep    = gi + (size_t)NCLK*G3;     // 64*400
  float* whhT4       = user_rep + Bq*Fq;         // 1200*400
  // bf16 prep buffers live in gi's region (dead until gi_kernel, which runs after encode)
  __hip_bfloat16* convprep = (__hip_bfloat16*)gi;                 // 2*491520 bf16
  __hip_bfloat16* attprep  = (__hip_bfloat16*)(gi + 491520);      // 2*106496 bf16

  conv_prep_kernel<<<(2*30*16384 + 255)/256, 256, 0, stream>>>(c_cw, u_cw, convprep);
  att_prep_kernel<<<(2*13*8192 + 255)/256, 256, 0, stream>>>(c_aW, u_aW, attprep);
  whh_transpose_kernel<<<(G3*Fq + 1023)/1024, 1024, 0, stream>>>(whh, whhT4);

  encode_mfma_kernel<<<(NCAND + NCLK)/4, 512, 0, stream>>>(
      cand_emb, clk_emb, convprep, attprep,
      c_cb, c_ab, c_aq, c_lg, c_lb,
      u_cb, u_ab, u_aq, u_lg, u_lb,
      cand_rep, clicked_rep);

  gi_kernel<<<dim3(NCLK/64, 5), 256, 0, stream>>>(clicked_rep, wih, bih, gi);

  gru_kernel<<<Bq, 1024, 0, stream>>>(gi, whhT4, bhh, lens, user_rep);

  score_kernel<<<NCAND, 64, 0, stream>>>(cand_rep, user_rep, (float*)d_out);
}